// Round 1
// baseline (1496.290 us; speedup 1.0000x reference)
//
#include <hip/hip_runtime.h>
#include <math.h>

// Problem constants (fixed by reference): D=128, H=8, dh=16.

__global__ __launch_bounds__(128) void qkv_kernel(
    const float* __restrict__ x, const float* __restrict__ WQ,
    const float* __restrict__ WK, const float* __restrict__ WV,
    float* __restrict__ Q, float* __restrict__ K, float* __restrict__ V,
    int N)
{
    const int t = threadIdx.x;
    const int row = blockIdx.x;
    if (row >= N) return;
    __shared__ float xs[128];
    xs[t] = x[(size_t)row * 128 + t];
    __syncthreads();
    float aq = 0.f, ak = 0.f, av = 0.f;
    const float4* xs4 = (const float4*)xs;
#pragma unroll 4
    for (int k4 = 0; k4 < 32; ++k4) {
        float4 xv = xs4[k4];
        const float* wq = WQ + (size_t)(k4 * 4) * 128 + t;
        const float* wk = WK + (size_t)(k4 * 4) * 128 + t;
        const float* wv = WV + (size_t)(k4 * 4) * 128 + t;
        aq += xv.x * wq[0];   ak += xv.x * wk[0];   av += xv.x * wv[0];
        aq += xv.y * wq[128]; ak += xv.y * wk[128]; av += xv.y * wv[128];
        aq += xv.z * wq[256]; ak += xv.z * wk[256]; av += xv.z * wv[256];
        aq += xv.w * wq[384]; ak += xv.w * wk[384]; av += xv.w * wv[384];
    }
    const size_t o = (size_t)row * 128 + t;
    Q[o] = aq; K[o] = ak; V[o] = av;
}

// 4 edges per 128-thread block. Thread t owns feature t (head t>>4, dim t&15).
__global__ __launch_bounds__(128) void edge_kernel(
    const float* __restrict__ edge_attr, const float* __restrict__ WE,
    const float* __restrict__ Qp, const float* __restrict__ Kp, const float* __restrict__ Vp,
    const int* __restrict__ src_idx, const int* __restrict__ dst_idx,
    float* __restrict__ wV, float* __restrict__ Z, int E)
{
    const int t = threadIdx.x;
    const long e0 = (long)blockIdx.x * 4;
    __shared__ float ea[4][128];
#pragma unroll
    for (int i = 0; i < 4; ++i) {
        long e = e0 + i;
        if (e < E) ea[i][t] = edge_attr[(size_t)e * 128 + t];
    }
    __syncthreads();

    float acc0 = 0.f, acc1 = 0.f, acc2 = 0.f, acc3 = 0.f;
    const float4* ea40 = (const float4*)ea[0];
    const float4* ea41 = (const float4*)ea[1];
    const float4* ea42 = (const float4*)ea[2];
    const float4* ea43 = (const float4*)ea[3];
#pragma unroll 4
    for (int k4 = 0; k4 < 32; ++k4) {
        const float* w = WE + (size_t)(k4 * 4) * 128 + t;
        float w0 = w[0], w1 = w[128], w2 = w[256], w3 = w[384];
        float4 a;
        a = ea40[k4]; acc0 += a.x * w0 + a.y * w1 + a.z * w2 + a.w * w3;
        a = ea41[k4]; acc1 += a.x * w0 + a.y * w1 + a.z * w2 + a.w * w3;
        a = ea42[k4]; acc2 += a.x * w0 + a.y * w1 + a.z * w2 + a.w * w3;
        a = ea43[k4]; acc3 += a.x * w0 + a.y * w1 + a.z * w2 + a.w * w3;
    }
    float accs[4] = {acc0, acc1, acc2, acc3};

    const int hd = t >> 4;
    const int dd = t & 15;
#pragma unroll
    for (int i = 0; i < 4; ++i) {
        long e = e0 + i;
        if (e >= E) break;
        const int s  = src_idx[e];
        const int dn = dst_idx[e];
        const float q = Qp[(size_t)dn * 128 + t];
        const float k = Kp[(size_t)s * 128 + t];
        const float v = Vp[(size_t)s * 128 + t];
        float p = k * q * 0.25f * accs[i];   // 1/sqrt(dh) = 0.25
        p += __shfl_xor(p, 1, 16);
        p += __shfl_xor(p, 2, 16);
        p += __shfl_xor(p, 4, 16);
        p += __shfl_xor(p, 8, 16);
        const float sc = expf(fminf(fmaxf(p, -5.f), 5.f));
        atomicAdd(&wV[(size_t)dn * 128 + t], v * sc);
        if (dd == 0) atomicAdd(&Z[(size_t)dn * 8 + hd], sc);
    }
}

// h = x + wV/(Z+eps); also accumulate per-column sum and sumsq.
__global__ __launch_bounds__(256) void h_stats_kernel(
    const float* __restrict__ x, const float* __restrict__ wV, const float* __restrict__ Z,
    float* __restrict__ h, float* __restrict__ sums, int N)
{
    const int c = threadIdx.x & 127;
    const int half = threadIdx.x >> 7;
    float s1 = 0.f, s2 = 0.f;
    for (int r = blockIdx.x * 2 + half; r < N; r += gridDim.x * 2) {
        const float z = Z[(size_t)r * 8 + (c >> 4)];
        const float hv = x[(size_t)r * 128 + c] + wV[(size_t)r * 128 + c] / (z + 1e-6f);
        h[(size_t)r * 128 + c] = hv;
        s1 += hv;
        s2 += hv * hv;
    }
    __shared__ float red[256];
    red[threadIdx.x] = s1;
    __syncthreads();
    if (half == 0) atomicAdd(&sums[c], s1 + red[c + 128]);
    __syncthreads();
    red[threadIdx.x] = s2;
    __syncthreads();
    if (half == 0) atomicAdd(&sums[128 + c], s2 + red[c + 128]);
}

__global__ void bn_scale_kernel(
    const float* __restrict__ sums,
    const float* __restrict__ gamma, const float* __restrict__ beta,
    float* __restrict__ sb, int N)
{
    const int c = threadIdx.x;  // 128 threads
    const float invN = 1.0f / (float)N;
    const float mean = sums[c] * invN;
    const float var = sums[128 + c] * invN - mean * mean;
    const float sc = gamma[c] * rsqrtf(var + 1e-5f);
    sb[c] = sc;
    sb[128 + c] = beta[c] - mean * sc;
}

__global__ __launch_bounds__(256) void bn_apply_kernel(
    const float* __restrict__ h, const float* __restrict__ sb,
    float* __restrict__ out, size_t total)
{
    __shared__ float ssb[256];
    ssb[threadIdx.x] = sb[threadIdx.x];
    __syncthreads();
    const size_t n4 = total / 4;
    const float4* h4 = (const float4*)h;
    float4* o4 = (float4*)out;
    for (size_t i = (size_t)blockIdx.x * blockDim.x + threadIdx.x; i < n4;
         i += (size_t)gridDim.x * blockDim.x) {
        const int c4 = (int)(i & 31) * 4;  // 32 float4 per 128-wide row
        float4 v = h4[i];
        v.x = v.x * ssb[c4 + 0] + ssb[128 + c4 + 0];
        v.y = v.y * ssb[c4 + 1] + ssb[128 + c4 + 1];
        v.z = v.z * ssb[c4 + 2] + ssb[128 + c4 + 2];
        v.w = v.w * ssb[c4 + 3] + ssb[128 + c4 + 3];
        o4[i] = v;
    }
}

extern "C" void kernel_launch(void* const* d_in, const int* in_sizes, int n_in,
                              void* d_out, int out_size, void* d_ws, size_t ws_size,
                              hipStream_t stream)
{
    const float* x         = (const float*)d_in[0];
    const float* edge_attr = (const float*)d_in[1];
    const float* WQ        = (const float*)d_in[2];
    const float* WK        = (const float*)d_in[3];
    const float* WV        = (const float*)d_in[4];
    const float* WE        = (const float*)d_in[5];
    const float* gamma     = (const float*)d_in[6];
    const float* beta      = (const float*)d_in[7];
    const int*   eidx      = (const int*)d_in[8];

    const int N = in_sizes[0] / 128;
    const int E = in_sizes[8] / 2;
    const int* src = eidx;       // edge_index[0] = source
    const int* dst = eidx + E;   // edge_index[1] = destination

    float* ws = (float*)d_ws;
    const size_t NB = (size_t)N * 128;
    float* Q    = ws;
    float* K    = ws + NB;
    float* V    = ws + 2 * NB;
    float* wV   = ws + 3 * NB;
    float* Z    = ws + 4 * NB;            // N*8
    float* sums = Z + (size_t)N * 8;      // 256
    float* sb   = sums + 256;             // 256

    // Zero the accumulation regions (ws is poisoned 0xAA before every launch).
    hipMemsetAsync(wV, 0, (NB + (size_t)N * 8 + 256) * sizeof(float), stream);

    qkv_kernel<<<N, 128, 0, stream>>>(x, WQ, WK, WV, Q, K, V, N);
    edge_kernel<<<(E + 3) / 4, 128, 0, stream>>>(edge_attr, WE, Q, K, V, src, dst, wV, Z, E);
    h_stats_kernel<<<1024, 256, 0, stream>>>(x, wV, Z, (float*)d_out, sums, N);
    bn_scale_kernel<<<1, 128, 0, stream>>>(sums, gamma, beta, sb, N);
    bn_apply_kernel<<<2048, 256, 0, stream>>>((const float*)d_out, sb, (float*)d_out,
                                              (size_t)N * 128);
}